// Round 1
// 490.762 us; speedup vs baseline: 1.0143x; 1.0143x over previous
//
#include <hip/hip_runtime.h>
#include <float.h>

#define LRELU(v) ((v) > 0.0f ? (v) : 0.01f * (v))

// Order-preserving float->int map (involution): a<b  <=>  f2ord(a)<f2ord(b)
__device__ __forceinline__ int f2ord(float f) {
    int i = __float_as_int(f);
    return (i >= 0) ? i : (int)(0x80000000u - (unsigned int)i);
}
__device__ __forceinline__ float ord2f(int m) {
    int i = (m >= 0) ? m : (int)(0x80000000u - (unsigned int)m);
    return __int_as_float(i);
}

// All three input linears in one dispatch (range-partitioned; boundaries are
// multiples of 256 so branches are wave-uniform). Tail blocks (idx >= TOT)
// zero the CSR histogram buffer — independent work, saves a dispatch.
__global__ void lin3(const float* __restrict__ xf, const float* __restrict__ xe,
                     const float* __restrict__ xv,
                     const float* __restrict__ Wf, const float* __restrict__ bf,
                     const float* __restrict__ We, const float* __restrict__ be,
                     const float* __restrict__ Wv, const float* __restrict__ bv,
                     float* __restrict__ of, float* __restrict__ oe,
                     float* __restrict__ ov, int* __restrict__ cnt) {
    int idx = blockIdx.x * 256 + threadIdx.x;
    const int NFC = 5120000, NEC = 10240000, NVC = 5120000;
    const int TOT = NFC + NEC + NVC;      // 20,480,000 (multiple of 256)
    if (idx >= TOT) {
        int ci = idx - TOT;
        if (ci < 280832) cnt[ci] = 0;     // 1097*256 tail blocks
        return;
    }
    const float* x; const float* W; const float* bb; float* o; int cin; int loc;
    if (idx < NFC)              { x = xf; W = Wf; bb = bf; o = of; cin = 4; loc = idx; }
    else if (idx < NFC + NEC)   { x = xe; W = We; bb = be; o = oe; cin = 6; loc = idx - NFC; }
    else                        { x = xv; W = Wv; bb = bv; o = ov; cin = 3; loc = idx - NFC - NEC; }
    int c = loc & 31, r = loc >> 5;
    float acc = bb[c];
    for (int k = 0; k < cin; ++k)
        acc = fmaf(x[r * cin + k], W[k * 32 + c], acc);
    o[loc] = LRELU(acc);
}

// ---------------- CSR build (5 graphs batched) ----------------
//   g: 0=F2E 1=E2V 2=FF 3=E2F 4=V2E
//   E:      160000,160000,240000,160000,160000 (total 880000)
//   cntOff: 0, 80128, 120320, 160512, 200704  (total 280832 = 1097*256)
//   blkOff: 0, 313, 470, 627, 784             (1097 blocks)
//   csrOff: 0, 160000, 320000, 560000, 720000

__global__ void hist5(const int* __restrict__ e0, const int* __restrict__ e1,
                      const int* __restrict__ e2, const int* __restrict__ e3,
                      const int* __restrict__ e4, int* __restrict__ cnt) {
    int idx = blockIdx.x * 256 + threadIdx.x;
    if (idx >= 880000) return;
    const int cum[6]  = {0, 160000, 320000, 560000, 720000, 880000};
    const int cOff[5] = {0, 80128, 120320, 160512, 200704};
    const int Eg[5]   = {160000, 160000, 240000, 160000, 160000};
    const int* eds[5] = {e0, e1, e2, e3, e4};
    int g = 0;
#pragma unroll
    for (int k = 1; k < 5; ++k) g += (idx >= cum[k]);
    int e = idx - cum[g];
    int d = eds[g][Eg[g] + e];
    atomicAdd(&cnt[cOff[g] + d], 1);
}

__global__ void scan_blocks(int* __restrict__ cnt, int* __restrict__ bsum) {
    __shared__ int buf[256];
    int t = threadIdx.x;
    int i = blockIdx.x * 256 + t;
    int v = cnt[i];
    buf[t] = v;
    __syncthreads();
    for (int off = 1; off < 256; off <<= 1) {
        int x = (t >= off) ? buf[t - off] : 0;
        __syncthreads();
        buf[t] += x;
        __syncthreads();
    }
    cnt[i] = buf[t] - v;
    if (t == 255) bsum[blockIdx.x] = buf[255];
}

__global__ void scan_bsum(int* __restrict__ bsum) {
    __shared__ int buf[512];
    const int blkOff[5] = {0, 313, 470, 627, 784};
    const int nb[5]     = {313, 157, 157, 157, 313};
    int t = threadIdx.x;
    for (int g = 0; g < 5; ++g) {
        int v = (t < nb[g]) ? bsum[blkOff[g] + t] : 0;
        buf[t] = v;
        __syncthreads();
        for (int off = 1; off < 512; off <<= 1) {
            int x = (t >= off) ? buf[t - off] : 0;
            __syncthreads();
            buf[t] += x;
            __syncthreads();
        }
        if (t < nb[g]) bsum[blkOff[g] + t] = buf[t] - v;
        __syncthreads();
    }
}

__global__ void scan_add(int* __restrict__ cnt, const int* __restrict__ bsum,
                         int* __restrict__ cursor) {
    int i = blockIdx.x * 256 + threadIdx.x;
    int v = cnt[i] + bsum[blockIdx.x];
    cnt[i] = v;
    cursor[i] = v;
}

__global__ void fill_csr(const int* __restrict__ e0, const int* __restrict__ e1,
                         const int* __restrict__ e2, const int* __restrict__ e3,
                         const int* __restrict__ e4, int* __restrict__ cursor,
                         int* __restrict__ csr) {
    int idx = blockIdx.x * 256 + threadIdx.x;
    if (idx >= 880000) return;
    const int cum[6]   = {0, 160000, 320000, 560000, 720000, 880000};
    const int cOff[5]  = {0, 80128, 120320, 160512, 200704};
    const int csOff[5] = {0, 160000, 320000, 560000, 720000};
    const int Eg[5]    = {160000, 160000, 240000, 160000, 160000};
    const int* eds[5]  = {e0, e1, e2, e3, e4};
    int g = 0;
#pragma unroll
    for (int k = 1; k < 5; ++k) g += (idx >= cum[k]);
    int e = idx - cum[g];
    int s = eds[g][e];
    int d = eds[g][Eg[g] + e];
    int pos = atomicAdd(&cursor[cOff[g] + d], 1);
    csr[csOff[g] + pos] = s;
}

// ---------------- fused conv ----------------
struct ConvJob {
    const float* xsrc; const float* xdst;
    const int* starts; const int* csr;
    const float* W; const float* bias; float* out;
    int Ns; int Nd; int blkStart;
};
struct ConvJobs { ConvJob e[3]; };

// 32 dst nodes / block of 256 threads.
// Phase 1: edge-parallel pull-gather. Edges of the block staged in LDS as
//          (src<<6)|dst_local (dst found by 5-step bsearch in starts); then
//          each thread loops edges with independent float4 gathers +
//          ds_min into smxi (f2ord-mapped running min per (node,b,c)).
//          Row stride 33 ints (NOT 36/32): bank = (4*dl + b + 4*c4 + i)%32,
//          so the 32 lanes of one (edge,batch) span all 32 banks; the 2nd
//          in-flight edge makes it 2-way which is free. Stride 36 was an
//          8-way conflict on EVERY atomic (SQ_LDS_BANK_CONFLICT 1.05e7).
// Phase 2: one h-row per lane (wave w: rows (w&1)*64+lane, channel half
//          (w>>1)*16 — wave-uniform via readfirstlane so W/bias loads
//          scalarize to s_load; k-loop is pure v_fmac). smxi reads are
//          scalar b32 (row base only 4B-aligned at stride 33); bank =
//          (r+q)%32 across consecutive r -> conflict-free.
// NOTE: no min-occupancy bound — R4's (256,4) capped VGPRs -> scratch spill.
__global__ __launch_bounds__(256, 1)
void conv_fused(ConvJobs jobs) {
    __shared__ int smxi[128][33];   // [node_local*4+b][c] f2ord mins; 132B rows
    __shared__ int sedge[1024];     // (src<<6)|dst_local  (max block edges ~300)
    __shared__ int sst[33];
    int t = threadIdx.x;
    int bid = blockIdx.x;
    int g = (bid >= jobs.e[2].blkStart) ? 2 : (bid >= jobs.e[1].blkStart) ? 1 : 0;
    const float* xsrc  = jobs.e[g].xsrc;
    const float* xdst  = jobs.e[g].xdst;
    const int*   starts= jobs.e[g].starts;
    const int*   csr   = jobs.e[g].csr;
    const float* W     = jobs.e[g].W;
    const float* bias  = jobs.e[g].bias;
    float*       out   = jobs.e[g].out;
    int Ns = jobs.e[g].Ns, Nd = jobs.e[g].Nd;
    int base = (bid - jobs.e[g].blkStart) * 32;

    if (t < 33) sst[t] = starts[base + t];
    for (int i = t; i < 128 * 33; i += 256) ((int*)smxi)[i] = 0x7FFFFFFF;
    __syncthreads();

    int E0 = sst[0];
    int m  = sst[32] - E0;
    // stage edges (coalesced csr read + 5-step bsearch for dst-local)
    for (int j = t; j < m; j += 256) {
        int jg = E0 + j;
        int s = csr[jg];
        int lo = 0, hi = 32;
#pragma unroll
        for (int it = 0; it < 5; ++it) {
            int mid = (lo + hi) >> 1;
            if (sst[mid] <= jg) lo = mid; else hi = mid;
        }
        sedge[j] = (s << 6) | lo;
    }
    __syncthreads();

    // phase 1: independent gathers + LDS atomic min
    {
        int c4 = t & 7;            // channel quad
        int b  = (t >> 3) & 3;
        int el = t >> 5;           // edge lane 0..7
        const float* xsb = xsrc + (size_t)b * Ns * 32 + c4 * 4;
        for (int j = el; j < m; j += 16) {
            {
                int se = sedge[j];
                int dl = se & 63, s = se >> 6;
                float4 v = *(const float4*)(xsb + (size_t)s * 32);
                int* mr = &smxi[dl * 4 + b][c4 * 4];
                atomicMin(&mr[0], f2ord(v.x));
                atomicMin(&mr[1], f2ord(v.y));
                atomicMin(&mr[2], f2ord(v.z));
                atomicMin(&mr[3], f2ord(v.w));
            }
            int j2 = j + 8;
            if (j2 < m) {
                int se = sedge[j2];
                int dl = se & 63, s = se >> 6;
                float4 v = *(const float4*)(xsb + (size_t)s * 32);
                int* mr = &smxi[dl * 4 + b][c4 * 4];
                atomicMin(&mr[0], f2ord(v.x));
                atomicMin(&mr[1], f2ord(v.y));
                atomicMin(&mr[2], f2ord(v.z));
                atomicMin(&mr[3], f2ord(v.w));
            }
        }
    }
    __syncthreads();

    // phase 2: out = xd + lrelu([xd|mx] @ W + bias)
    int w    = t >> 6;
    int lane = t & 63;
    int r    = (w & 1) * 64 + lane;                       // row 0..127
    int c0   = __builtin_amdgcn_readfirstlane((w >> 1) * 16);  // wave-uniform
    int nl = r >> 2, b2 = r & 3;
    int d  = base + nl;
    int deg = sst[nl + 1] - sst[nl];
    const float* xdp = xdst + ((size_t)b2 * Nd + d) * 32;

    float xd[32];
#pragma unroll
    for (int q = 0; q < 8; ++q) {
        float4 v = ((const float4*)xdp)[q];
        xd[4*q] = v.x; xd[4*q+1] = v.y; xd[4*q+2] = v.z; xd[4*q+3] = v.w;
    }
    float mx[32];
    bool has = (deg > 0);
#pragma unroll
    for (int q = 0; q < 32; ++q) {
        int iv = smxi[r][q];
        mx[q] = has ? (xd[q] - ord2f(iv)) : 0.0f;
    }
    const float* Wc = W + c0;
    float acc[16];
#pragma unroll
    for (int jj = 0; jj < 16; ++jj) acc[jj] = bias[c0 + jj];
#pragma unroll
    for (int k = 0; k < 64; ++k) {
        float hk = (k < 32) ? xd[k] : mx[k - 32];   // resolved at unroll time
        const float4* wr = (const float4*)(Wc + k * 32);
        float4 w0 = wr[0], w1 = wr[1], w2 = wr[2], w3 = wr[3];
        acc[0]  = fmaf(hk, w0.x, acc[0]);  acc[1]  = fmaf(hk, w0.y, acc[1]);
        acc[2]  = fmaf(hk, w0.z, acc[2]);  acc[3]  = fmaf(hk, w0.w, acc[3]);
        acc[4]  = fmaf(hk, w1.x, acc[4]);  acc[5]  = fmaf(hk, w1.y, acc[5]);
        acc[6]  = fmaf(hk, w1.z, acc[6]);  acc[7]  = fmaf(hk, w1.w, acc[7]);
        acc[8]  = fmaf(hk, w2.x, acc[8]);  acc[9]  = fmaf(hk, w2.y, acc[9]);
        acc[10] = fmaf(hk, w2.z, acc[10]); acc[11] = fmaf(hk, w2.w, acc[11]);
        acc[12] = fmaf(hk, w3.x, acc[12]); acc[13] = fmaf(hk, w3.y, acc[13]);
        acc[14] = fmaf(hk, w3.z, acc[14]); acc[15] = fmaf(hk, w3.w, acc[15]);
    }
    float* op = out + ((size_t)b2 * Nd + d) * 32 + c0;
    const float4* xres = (const float4*)(xdp + c0);
#pragma unroll
    for (int q = 0; q < 4; ++q) {
        float4 xv = xres[q];
        float4 o;
        float a0 = acc[4*q], a1 = acc[4*q+1], a2 = acc[4*q+2], a3 = acc[4*q+3];
        o.x = xv.x + LRELU(a0); o.y = xv.y + LRELU(a1);
        o.z = xv.z + LRELU(a2); o.w = xv.w + LRELU(a3);
        ((float4*)op)[q] = o;
    }
}

extern "C" void kernel_launch(void* const* d_in, const int* in_sizes, int n_in,
                              void* d_out, int out_size, void* d_ws, size_t ws_size,
                              hipStream_t stream) {
    const float* x_f = (const float*)d_in[0];
    const float* x_e = (const float*)d_in[1];
    const float* x_v = (const float*)d_in[2];
    // d_in[3] = index_id (identity arange) — unused
    const int* fe = (const int*)d_in[4];
    const int* ev = (const int*)d_in[5];
    const int* ff = (const int*)d_in[6];
    const int* ef = (const int*)d_in[7];
    const int* ve = (const int*)d_in[8];
    const float* Wf = (const float*)d_in[9];
    const float* bf = (const float*)d_in[10];
    const float* We = (const float*)d_in[11];
    const float* be = (const float*)d_in[12];
    const float* Wv = (const float*)d_in[13];
    const float* bv = (const float*)d_in[14];
    const float* W_f2e = (const float*)d_in[15];
    const float* b_f2e = (const float*)d_in[16];
    const float* W_e2v = (const float*)d_in[17];
    const float* b_e2v = (const float*)d_in[18];
    const float* W_ff  = (const float*)d_in[19];
    const float* b_ff  = (const float*)d_in[20];
    const float* W_e2f = (const float*)d_in[21];
    const float* b_e2f = (const float*)d_in[22];
    const float* W_v2e = (const float*)d_in[23];
    const float* b_v2e = (const float*)d_in[24];

    const int B = 4, Nf = 40000, Ne = 80000, Nv = 40000;
    const int NFC = B * Nf * 32;
    const int NEC = B * Ne * 32;
    const int NVC = B * Nv * 32;
    const int CNT_TOTAL = 280832;   // 1097 * 256
    const int NBLK = 1097;
    const int E_TOTAL = 880000;
    const int INT_WORDS = 2 * CNT_TOTAL + 1152 + E_TOTAL;

    float* oxf = (float*)d_out;        // xf1 then final xf
    float* oxe = oxf + NFC;            // final xe
    float* oxv = oxe + NEC;            // xv0 then final xv

    // Plan A (merged epilogue) routes xe1 through ws so E2F and V2E can run
    // in ONE dispatch (removes the xe1 read/overwrite anti-dependence).
    // Needs (NFC + 2*NEC) floats + int area; fall back to 3-launch if ws small.
    size_t needA = (size_t)(NFC + 2 * NEC) * 4 + (size_t)INT_WORDS * 4;
    bool merged = ws_size >= needA;

    float* ws  = (float*)d_ws;
    float* xf0 = ws;
    float* xe0 = ws + NFC;
    float* xe1 = merged ? (ws + NFC + NEC) : oxe;  // where F2E writes xe1
    int* cnt    = (int*)(merged ? (ws + NFC + 2 * NEC) : (ws + NFC + NEC));
    int* cursor = cnt + CNT_TOTAL;
    int* bsum   = cursor + CNT_TOTAL;
    int* csr    = bsum + 1152;

    const int T = 256;
    auto blk = [](int n) { return (n + 255) / 256; };

    // lin3 + histogram-zero fused (tail blocks)
    lin3<<<blk(NFC + NEC + NVC) + NBLK, T, 0, stream>>>(
        x_f, x_e, x_v, Wf, bf, We, be, Wv, bv, xf0, xe0, oxv, cnt);

    hist5<<<blk(E_TOTAL), T, 0, stream>>>(fe, ev, ff, ef, ve, cnt);
    scan_blocks<<<NBLK, 256, 0, stream>>>(cnt, bsum);
    scan_bsum<<<1, 512, 0, stream>>>(bsum);
    scan_add<<<NBLK, 256, 0, stream>>>(cnt, bsum, cursor);
    fill_csr<<<blk(E_TOTAL), T, 0, stream>>>(fe, ev, ff, ef, ve, cursor, csr);

    int* st_f2e = cnt;            int* cs_f2e = csr;
    int* st_e2v = cnt + 80128;    int* cs_e2v = csr + 160000;
    int* st_ff  = cnt + 120320;   int* cs_ff  = csr + 320000;
    int* st_e2f = cnt + 160512;   int* cs_e2f = csr + 560000;
    int* st_v2e = cnt + 200704;   int* cs_v2e = csr + 720000;

    // Launch 1: F2E + E2V + FF (mutually independent)
    //   F2E: src xf0, dst xe0 -> xe1 (ws in plan A, oxe in plan B)
    //   E2V: src xe0, dst oxv(=xv0) -> oxv in place (final xv)
    //   FF : src xf0, dst xf0 -> oxf (= xf1)
    {
        ConvJobs j;
        j.e[0] = {xf0, xe0, st_f2e, cs_f2e, W_f2e, b_f2e, xe1, Nf, Ne, 0};
        j.e[1] = {xe0, oxv, st_e2v, cs_e2v, W_e2v, b_e2v, oxv, Ne, Nv, 2500};
        j.e[2] = {xf0, xf0, st_ff,  cs_ff,  W_ff,  b_ff,  oxf, Nf, Nf, 3750};
        conv_fused<<<5000, 256, 0, stream>>>(j);
    }
    if (merged) {
        // Launch 2: E2F + V2E in one dispatch.
        //   E2F: src xe1(ws), dst oxf(=xf1) -> oxf in place (final xf)
        //   V2E: src oxv(final xv), dst xe1(ws) -> oxe (final xe)
        // No race: xe1 is read-only here; V2E writes a DIFFERENT buffer (oxe).
        ConvJobs j;
        j.e[0] = {xe1, oxf, st_e2f, cs_e2f, W_e2f, b_e2f, oxf, Ne, Nf, 0};
        j.e[1] = {oxv, xe1, st_v2e, cs_v2e, W_v2e, b_v2e, oxe, Nv, Ne, 1250};
        j.e[2] = j.e[0]; j.e[2].blkStart = 0x7FFFFFFF;
        conv_fused<<<3750, 256, 0, stream>>>(j);
    } else {
        // Plan B: original serialized epilogue (xe1 lives in oxe, in-place V2E)
        {
            ConvJobs j;
            j.e[0] = {oxe, oxf, st_e2f, cs_e2f, W_e2f, b_e2f, oxf, Ne, Nf, 0};
            j.e[1] = j.e[0]; j.e[1].blkStart = 0x7FFFFFFF;
            j.e[2] = j.e[0]; j.e[2].blkStart = 0x7FFFFFFF;
            conv_fused<<<1250, 256, 0, stream>>>(j);
        }
        {
            ConvJobs j;
            j.e[0] = {oxv, oxe, st_v2e, cs_v2e, W_v2e, b_v2e, oxe, Nv, Ne, 0};
            j.e[1] = j.e[0]; j.e[1].blkStart = 0x7FFFFFFF;
            j.e[2] = j.e[0]; j.e[2].blkStart = 0x7FFFFFFF;
            conv_fused<<<2500, 256, 0, stream>>>(j);
        }
    }
}

// Round 2
// 479.109 us; speedup vs baseline: 1.0390x; 1.0243x over previous
//
#include <hip/hip_runtime.h>
#include <float.h>

#define LRELU(v) ((v) > 0.0f ? (v) : 0.01f * (v))

// Order-preserving float->int map (involution): a<b  <=>  f2ord(a)<f2ord(b)
__device__ __forceinline__ int f2ord(float f) {
    int i = __float_as_int(f);
    return (i >= 0) ? i : (int)(0x80000000u - (unsigned int)i);
}
__device__ __forceinline__ float ord2f(int m) {
    int i = (m >= 0) ? m : (int)(0x80000000u - (unsigned int)m);
    return __int_as_float(i);
}

// All three input linears in one dispatch (range-partitioned; boundaries are
// multiples of 256 so branches are wave-uniform). Tail blocks (idx >= TOT)
// zero the CSR histogram buffer — independent work, saves a dispatch.
__global__ void lin3(const float* __restrict__ xf, const float* __restrict__ xe,
                     const float* __restrict__ xv,
                     const float* __restrict__ Wf, const float* __restrict__ bf,
                     const float* __restrict__ We, const float* __restrict__ be,
                     const float* __restrict__ Wv, const float* __restrict__ bv,
                     float* __restrict__ of, float* __restrict__ oe,
                     float* __restrict__ ov, int* __restrict__ cnt) {
    int idx = blockIdx.x * 256 + threadIdx.x;
    const int NFC = 5120000, NEC = 10240000, NVC = 5120000;
    const int TOT = NFC + NEC + NVC;      // 20,480,000 (multiple of 256)
    if (idx >= TOT) {
        int ci = idx - TOT;
        if (ci < 280832) cnt[ci] = 0;     // 1097*256 tail blocks
        return;
    }
    const float* x; const float* W; const float* bb; float* o; int cin; int loc;
    if (idx < NFC)              { x = xf; W = Wf; bb = bf; o = of; cin = 4; loc = idx; }
    else if (idx < NFC + NEC)   { x = xe; W = We; bb = be; o = oe; cin = 6; loc = idx - NFC; }
    else                        { x = xv; W = Wv; bb = bv; o = ov; cin = 3; loc = idx - NFC - NEC; }
    int c = loc & 31, r = loc >> 5;
    float acc = bb[c];
    for (int k = 0; k < cin; ++k)
        acc = fmaf(x[r * cin + k], W[k * 32 + c], acc);
    o[loc] = LRELU(acc);
}

// ---------------- CSR build (5 graphs batched) ----------------
//   g: 0=F2E 1=E2V 2=FF 3=E2F 4=V2E
//   E:      160000,160000,240000,160000,160000 (total 880000)
//   cntOff: 0, 80128, 120320, 160512, 200704  (total 280832 = 1097*256)
//   blkOff: 0, 313, 470, 627, 784             (1097 blocks)
//   csrOff: 0, 160000, 320000, 560000, 720000

__global__ void hist5(const int* __restrict__ e0, const int* __restrict__ e1,
                      const int* __restrict__ e2, const int* __restrict__ e3,
                      const int* __restrict__ e4, int* __restrict__ cnt) {
    int idx = blockIdx.x * 256 + threadIdx.x;
    if (idx >= 880000) return;
    const int cum[6]  = {0, 160000, 320000, 560000, 720000, 880000};
    const int cOff[5] = {0, 80128, 120320, 160512, 200704};
    const int Eg[5]   = {160000, 160000, 240000, 160000, 160000};
    const int* eds[5] = {e0, e1, e2, e3, e4};
    int g = 0;
#pragma unroll
    for (int k = 1; k < 5; ++k) g += (idx >= cum[k]);
    int e = idx - cum[g];
    int d = eds[g][Eg[g] + e];
    atomicAdd(&cnt[cOff[g] + d], 1);
}

__global__ void scan_blocks(int* __restrict__ cnt, int* __restrict__ bsum) {
    __shared__ int buf[256];
    int t = threadIdx.x;
    int i = blockIdx.x * 256 + t;
    int v = cnt[i];
    buf[t] = v;
    __syncthreads();
    for (int off = 1; off < 256; off <<= 1) {
        int x = (t >= off) ? buf[t - off] : 0;
        __syncthreads();
        buf[t] += x;
        __syncthreads();
    }
    cnt[i] = buf[t] - v;
    if (t == 255) bsum[blockIdx.x] = buf[255];
}

__global__ void scan_bsum(int* __restrict__ bsum) {
    __shared__ int buf[512];
    const int blkOff[5] = {0, 313, 470, 627, 784};
    const int nb[5]     = {313, 157, 157, 157, 313};
    int t = threadIdx.x;
    for (int g = 0; g < 5; ++g) {
        int v = (t < nb[g]) ? bsum[blkOff[g] + t] : 0;
        buf[t] = v;
        __syncthreads();
        for (int off = 1; off < 512; off <<= 1) {
            int x = (t >= off) ? buf[t - off] : 0;
            __syncthreads();
            buf[t] += x;
            __syncthreads();
        }
        if (t < nb[g]) bsum[blkOff[g] + t] = buf[t] - v;
        __syncthreads();
    }
}

__global__ void scan_add(int* __restrict__ cnt, const int* __restrict__ bsum,
                         int* __restrict__ cursor) {
    int i = blockIdx.x * 256 + threadIdx.x;
    int v = cnt[i] + bsum[blockIdx.x];
    cnt[i] = v;
    cursor[i] = v;
}

__global__ void fill_csr(const int* __restrict__ e0, const int* __restrict__ e1,
                         const int* __restrict__ e2, const int* __restrict__ e3,
                         const int* __restrict__ e4, int* __restrict__ cursor,
                         int* __restrict__ csr) {
    int idx = blockIdx.x * 256 + threadIdx.x;
    if (idx >= 880000) return;
    const int cum[6]   = {0, 160000, 320000, 560000, 720000, 880000};
    const int cOff[5]  = {0, 80128, 120320, 160512, 200704};
    const int csOff[5] = {0, 160000, 320000, 560000, 720000};
    const int Eg[5]    = {160000, 160000, 240000, 160000, 160000};
    const int* eds[5]  = {e0, e1, e2, e3, e4};
    int g = 0;
#pragma unroll
    for (int k = 1; k < 5; ++k) g += (idx >= cum[k]);
    int e = idx - cum[g];
    int s = eds[g][e];
    int d = eds[g][Eg[g] + e];
    int pos = atomicAdd(&cursor[cOff[g] + d], 1);
    csr[csOff[g] + pos] = s;
}

// ---------------- fused conv ----------------
struct ConvJob {
    const float* xsrc; const float* xdst;
    const int* starts; const int* csr;
    const float* W; const float* bias; float* out;
    int Ns; int Nd; int blkStart;
};
struct ConvJobs { ConvJob e[3]; };

// 32 dst nodes / block of 256 threads.
// Phase 1: edge-parallel pull-gather, 4-DEEP software pipeline. Edges staged
//          in LDS as (src<<6)|dst_local; each thread owns edge slots
//          {j, j+8, j+16, j+24} per iteration (stride 32) so FOUR independent
//          global_load_dwordx4 are in flight before the first atomic's
//          s_waitcnt. R1 measured 2.1 TB/s with the 2-deep pipe — Little's
//          law (≈12 waves/CU × 2×16B in flight, ~250ns latency) says request
//          depth, not any pipe, was the limit. Tail slots re-load slot-a's
//          address (same line, harmless); only atomics are predicated.
//          smxi row stride 33 ints: bank = (4*dl+b+4*c4+i)%32 -> the 32 lanes
//          of one edge span all 32 banks (stride 36 was 8-way conflicted;
//          conflicts now measured 0).
// Phase 2: one h-row per lane (wave w: rows (w&1)*64+lane, channel half
//          (w>>1)*16 — wave-uniform via readfirstlane so W/bias loads
//          scalarize to s_load; k-loop is pure v_fmac). smxi reads are
//          scalar b32 at stride 33 -> conflict-free.
// NOTE: no min-occupancy bound — a (256,4) bound capped VGPRs -> scratch spill.
__global__ __launch_bounds__(256, 1)
void conv_fused(ConvJobs jobs) {
    __shared__ int smxi[128][33];   // [node_local*4+b][c] f2ord mins; 132B rows
    __shared__ int sedge[1024];     // (src<<6)|dst_local  (max block edges ~300)
    __shared__ int sst[33];
    int t = threadIdx.x;
    int bid = blockIdx.x;
    int g = (bid >= jobs.e[2].blkStart) ? 2 : (bid >= jobs.e[1].blkStart) ? 1 : 0;
    const float* xsrc  = jobs.e[g].xsrc;
    const float* xdst  = jobs.e[g].xdst;
    const int*   starts= jobs.e[g].starts;
    const int*   csr   = jobs.e[g].csr;
    const float* W     = jobs.e[g].W;
    const float* bias  = jobs.e[g].bias;
    float*       out   = jobs.e[g].out;
    int Ns = jobs.e[g].Ns, Nd = jobs.e[g].Nd;
    int base = (bid - jobs.e[g].blkStart) * 32;

    if (t < 33) sst[t] = starts[base + t];
    for (int i = t; i < 128 * 33; i += 256) ((int*)smxi)[i] = 0x7FFFFFFF;
    __syncthreads();

    int E0 = sst[0];
    int m  = sst[32] - E0;
    // stage edges (coalesced csr read + 5-step bsearch for dst-local)
    for (int j = t; j < m; j += 256) {
        int jg = E0 + j;
        int s = csr[jg];
        int lo = 0, hi = 32;
#pragma unroll
        for (int it = 0; it < 5; ++it) {
            int mid = (lo + hi) >> 1;
            if (sst[mid] <= jg) lo = mid; else hi = mid;
        }
        sedge[j] = (s << 6) | lo;
    }
    __syncthreads();

    // phase 1: 4-deep pipelined gathers + LDS atomic min
    {
        int c4 = t & 7;            // channel quad
        int b  = (t >> 3) & 3;
        int el = t >> 5;           // edge lane 0..7
        const float* xsb = xsrc + (size_t)b * Ns * 32 + c4 * 4;
        for (int j = el; j < m; j += 32) {
            int jb = j + 8, jc = j + 16, jd = j + 24;
            bool pb = jb < m, pc = jc < m, pd = jd < m;
            int sea = sedge[j];
            int seb = pb ? sedge[jb] : sea;
            int sec = pc ? sedge[jc] : sea;
            int sed = pd ? sedge[jd] : sea;
            float4 va = *(const float4*)(xsb + (size_t)(sea >> 6) * 32);
            float4 vb = *(const float4*)(xsb + (size_t)(seb >> 6) * 32);
            float4 vc = *(const float4*)(xsb + (size_t)(sec >> 6) * 32);
            float4 vd = *(const float4*)(xsb + (size_t)(sed >> 6) * 32);
            {
                int* mr = &smxi[(sea & 63) * 4 + b][c4 * 4];
                atomicMin(&mr[0], f2ord(va.x));
                atomicMin(&mr[1], f2ord(va.y));
                atomicMin(&mr[2], f2ord(va.z));
                atomicMin(&mr[3], f2ord(va.w));
            }
            if (pb) {
                int* mr = &smxi[(seb & 63) * 4 + b][c4 * 4];
                atomicMin(&mr[0], f2ord(vb.x));
                atomicMin(&mr[1], f2ord(vb.y));
                atomicMin(&mr[2], f2ord(vb.z));
                atomicMin(&mr[3], f2ord(vb.w));
            }
            if (pc) {
                int* mr = &smxi[(sec & 63) * 4 + b][c4 * 4];
                atomicMin(&mr[0], f2ord(vc.x));
                atomicMin(&mr[1], f2ord(vc.y));
                atomicMin(&mr[2], f2ord(vc.z));
                atomicMin(&mr[3], f2ord(vc.w));
            }
            if (pd) {
                int* mr = &smxi[(sed & 63) * 4 + b][c4 * 4];
                atomicMin(&mr[0], f2ord(vd.x));
                atomicMin(&mr[1], f2ord(vd.y));
                atomicMin(&mr[2], f2ord(vd.z));
                atomicMin(&mr[3], f2ord(vd.w));
            }
        }
    }
    __syncthreads();

    // phase 2: out = xd + lrelu([xd|mx] @ W + bias)
    int w    = t >> 6;
    int lane = t & 63;
    int r    = (w & 1) * 64 + lane;                       // row 0..127
    int c0   = __builtin_amdgcn_readfirstlane((w >> 1) * 16);  // wave-uniform
    int nl = r >> 2, b2 = r & 3;
    int d  = base + nl;
    int deg = sst[nl + 1] - sst[nl];
    const float* xdp = xdst + ((size_t)b2 * Nd + d) * 32;

    float xd[32];
#pragma unroll
    for (int q = 0; q < 8; ++q) {
        float4 v = ((const float4*)xdp)[q];
        xd[4*q] = v.x; xd[4*q+1] = v.y; xd[4*q+2] = v.z; xd[4*q+3] = v.w;
    }
    float mx[32];
    bool has = (deg > 0);
#pragma unroll
    for (int q = 0; q < 32; ++q) {
        int iv = smxi[r][q];
        mx[q] = has ? (xd[q] - ord2f(iv)) : 0.0f;
    }
    const float* Wc = W + c0;
    float acc[16];
#pragma unroll
    for (int jj = 0; jj < 16; ++jj) acc[jj] = bias[c0 + jj];
#pragma unroll
    for (int k = 0; k < 64; ++k) {
        float hk = (k < 32) ? xd[k] : mx[k - 32];   // resolved at unroll time
        const float4* wr = (const float4*)(Wc + k * 32);
        float4 w0 = wr[0], w1 = wr[1], w2 = wr[2], w3 = wr[3];
        acc[0]  = fmaf(hk, w0.x, acc[0]);  acc[1]  = fmaf(hk, w0.y, acc[1]);
        acc[2]  = fmaf(hk, w0.z, acc[2]);  acc[3]  = fmaf(hk, w0.w, acc[3]);
        acc[4]  = fmaf(hk, w1.x, acc[4]);  acc[5]  = fmaf(hk, w1.y, acc[5]);
        acc[6]  = fmaf(hk, w1.z, acc[6]);  acc[7]  = fmaf(hk, w1.w, acc[7]);
        acc[8]  = fmaf(hk, w2.x, acc[8]);  acc[9]  = fmaf(hk, w2.y, acc[9]);
        acc[10] = fmaf(hk, w2.z, acc[10]); acc[11] = fmaf(hk, w2.w, acc[11]);
        acc[12] = fmaf(hk, w3.x, acc[12]); acc[13] = fmaf(hk, w3.y, acc[13]);
        acc[14] = fmaf(hk, w3.z, acc[14]); acc[15] = fmaf(hk, w3.w, acc[15]);
    }
    float* op = out + ((size_t)b2 * Nd + d) * 32 + c0;
    const float4* xres = (const float4*)(xdp + c0);
#pragma unroll
    for (int q = 0; q < 4; ++q) {
        float4 xv = xres[q];
        float4 o;
        float a0 = acc[4*q], a1 = acc[4*q+1], a2 = acc[4*q+2], a3 = acc[4*q+3];
        o.x = xv.x + LRELU(a0); o.y = xv.y + LRELU(a1);
        o.z = xv.z + LRELU(a2); o.w = xv.w + LRELU(a3);
        ((float4*)op)[q] = o;
    }
}

extern "C" void kernel_launch(void* const* d_in, const int* in_sizes, int n_in,
                              void* d_out, int out_size, void* d_ws, size_t ws_size,
                              hipStream_t stream) {
    const float* x_f = (const float*)d_in[0];
    const float* x_e = (const float*)d_in[1];
    const float* x_v = (const float*)d_in[2];
    // d_in[3] = index_id (identity arange) — unused
    const int* fe = (const int*)d_in[4];
    const int* ev = (const int*)d_in[5];
    const int* ff = (const int*)d_in[6];
    const int* ef = (const int*)d_in[7];
    const int* ve = (const int*)d_in[8];
    const float* Wf = (const float*)d_in[9];
    const float* bf = (const float*)d_in[10];
    const float* We = (const float*)d_in[11];
    const float* be = (const float*)d_in[12];
    const float* Wv = (const float*)d_in[13];
    const float* bv = (const float*)d_in[14];
    const float* W_f2e = (const float*)d_in[15];
    const float* b_f2e = (const float*)d_in[16];
    const float* W_e2v = (const float*)d_in[17];
    const float* b_e2v = (const float*)d_in[18];
    const float* W_ff  = (const float*)d_in[19];
    const float* b_ff  = (const float*)d_in[20];
    const float* W_e2f = (const float*)d_in[21];
    const float* b_e2f = (const float*)d_in[22];
    const float* W_v2e = (const float*)d_in[23];
    const float* b_v2e = (const float*)d_in[24];

    const int B = 4, Nf = 40000, Ne = 80000, Nv = 40000;
    const int NFC = B * Nf * 32;
    const int NEC = B * Ne * 32;
    const int NVC = B * Nv * 32;
    const int CNT_TOTAL = 280832;   // 1097 * 256
    const int NBLK = 1097;
    const int E_TOTAL = 880000;
    const int INT_WORDS = 2 * CNT_TOTAL + 1152 + E_TOTAL;

    float* oxf = (float*)d_out;        // xf1 then final xf
    float* oxe = oxf + NFC;            // final xe
    float* oxv = oxe + NEC;            // xv0 then final xv

    // Plan A (merged epilogue) routes xe1 through ws so E2F and V2E can run
    // in ONE dispatch (removes the xe1 read/overwrite anti-dependence).
    // Needs (NFC + 2*NEC) floats + int area; fall back to 3-launch if ws small.
    size_t needA = (size_t)(NFC + 2 * NEC) * 4 + (size_t)INT_WORDS * 4;
    bool merged = ws_size >= needA;

    float* ws  = (float*)d_ws;
    float* xf0 = ws;
    float* xe0 = ws + NFC;
    float* xe1 = merged ? (ws + NFC + NEC) : oxe;  // where F2E writes xe1
    int* cnt    = (int*)(merged ? (ws + NFC + 2 * NEC) : (ws + NFC + NEC));
    int* cursor = cnt + CNT_TOTAL;
    int* bsum   = cursor + CNT_TOTAL;
    int* csr    = bsum + 1152;

    const int T = 256;
    auto blk = [](int n) { return (n + 255) / 256; };

    // lin3 + histogram-zero fused (tail blocks)
    lin3<<<blk(NFC + NEC + NVC) + NBLK, T, 0, stream>>>(
        x_f, x_e, x_v, Wf, bf, We, be, Wv, bv, xf0, xe0, oxv, cnt);

    hist5<<<blk(E_TOTAL), T, 0, stream>>>(fe, ev, ff, ef, ve, cnt);
    scan_blocks<<<NBLK, 256, 0, stream>>>(cnt, bsum);
    scan_bsum<<<1, 512, 0, stream>>>(bsum);
    scan_add<<<NBLK, 256, 0, stream>>>(cnt, bsum, cursor);
    fill_csr<<<blk(E_TOTAL), T, 0, stream>>>(fe, ev, ff, ef, ve, cursor, csr);

    int* st_f2e = cnt;            int* cs_f2e = csr;
    int* st_e2v = cnt + 80128;    int* cs_e2v = csr + 160000;
    int* st_ff  = cnt + 120320;   int* cs_ff  = csr + 320000;
    int* st_e2f = cnt + 160512;   int* cs_e2f = csr + 560000;
    int* st_v2e = cnt + 200704;   int* cs_v2e = csr + 720000;

    // Launch 1: F2E + E2V + FF (mutually independent)
    //   F2E: src xf0, dst xe0 -> xe1 (ws in plan A, oxe in plan B)
    //   E2V: src xe0, dst oxv(=xv0) -> oxv in place (final xv)
    //   FF : src xf0, dst xf0 -> oxf (= xf1)
    {
        ConvJobs j;
        j.e[0] = {xf0, xe0, st_f2e, cs_f2e, W_f2e, b_f2e, xe1, Nf, Ne, 0};
        j.e[1] = {xe0, oxv, st_e2v, cs_e2v, W_e2v, b_e2v, oxv, Ne, Nv, 2500};
        j.e[2] = {xf0, xf0, st_ff,  cs_ff,  W_ff,  b_ff,  oxf, Nf, Nf, 3750};
        conv_fused<<<5000, 256, 0, stream>>>(j);
    }
    if (merged) {
        // Launch 2: E2F + V2E in one dispatch.
        //   E2F: src xe1(ws), dst oxf(=xf1) -> oxf in place (final xf)
        //   V2E: src oxv(final xv), dst xe1(ws) -> oxe (final xe)
        // No race: xe1 is read-only here; V2E writes a DIFFERENT buffer (oxe).
        ConvJobs j;
        j.e[0] = {xe1, oxf, st_e2f, cs_e2f, W_e2f, b_e2f, oxf, Ne, Nf, 0};
        j.e[1] = {oxv, xe1, st_v2e, cs_v2e, W_v2e, b_v2e, oxe, Nv, Ne, 1250};
        j.e[2] = j.e[0]; j.e[2].blkStart = 0x7FFFFFFF;
        conv_fused<<<3750, 256, 0, stream>>>(j);
    } else {
        // Plan B: original serialized epilogue (xe1 lives in oxe, in-place V2E)
        {
            ConvJobs j;
            j.e[0] = {oxe, oxf, st_e2f, cs_e2f, W_e2f, b_e2f, oxf, Ne, Nf, 0};
            j.e[1] = j.e[0]; j.e[1].blkStart = 0x7FFFFFFF;
            j.e[2] = j.e[0]; j.e[2].blkStart = 0x7FFFFFFF;
            conv_fused<<<1250, 256, 0, stream>>>(j);
        }
        {
            ConvJobs j;
            j.e[0] = {oxv, oxe, st_v2e, cs_v2e, W_v2e, b_v2e, oxe, Nv, Ne, 0};
            j.e[1] = j.e[0]; j.e[1].blkStart = 0x7FFFFFFF;
            j.e[2] = j.e[0]; j.e[2].blkStart = 0x7FFFFFFF;
            conv_fused<<<2500, 256, 0, stream>>>(j);
        }
    }
}